// Round 1
// baseline (598.548 us; speedup 1.0000x reference)
//
#include <hip/hip_runtime.h>

#define K_CODES 1024
#define D_DIM   256
#define HW      1024      // 32*32
#define N_ROWS  65536     // 64*1024
#define OUT_ELEMS 16777216  // 64*256*32*32

// -------- prep: ||e_k||^2 per code + zero the loss accumulator --------
__global__ void enorm_kernel(const float* __restrict__ emb,
                             float* __restrict__ eNorm,
                             float* __restrict__ lossAcc) {
    int k = blockIdx.x;          // 1024 blocks
    int lane = threadIdx.x;      // 64 threads
    const float4* row = reinterpret_cast<const float4*>(emb + k * D_DIM);
    float4 v = row[lane];        // d = lane*4 .. +3  (256 = 64*4)
    float s = v.x * v.x + v.y * v.y + v.z * v.z + v.w * v.w;
    #pragma unroll
    for (int off = 32; off > 0; off >>= 1) s += __shfl_down(s, off, 64);
    if (lane == 0) eNorm[k] = s;
    if (k == 0 && lane == 0) *lossAcc = 0.0f;
}

// -------- prep: transpose embedding [K][D] -> Et [D][K] --------
__global__ void transpose_kernel(const float* __restrict__ emb,
                                 float* __restrict__ Et) {
    __shared__ float tile[64][65];
    int k0 = blockIdx.x * 64;    // grid.x = 16
    int d0 = blockIdx.y * 64;    // grid.y = 4
    int t = threadIdx.x;         // 256
    #pragma unroll
    for (int p = 0; p < 16; ++p) {
        int kk = p * 4 + (t >> 6);
        int dd = t & 63;
        tile[kk][dd] = emb[(k0 + kk) * D_DIM + d0 + dd];
    }
    __syncthreads();
    #pragma unroll
    for (int p = 0; p < 16; ++p) {
        int dd = p * 4 + (t >> 6);
        int kk = t & 63;
        Et[(d0 + dd) * K_CODES + k0 + kk] = tile[kk][dd];
    }
}

// -------- main: fused distances + argmin + gather + out + loss --------
// grid: 512 blocks (128 rows each), block: 256 threads (16 tx x 16 ty)
__launch_bounds__(256, 2)
__global__ void vq_main(const float* __restrict__ lat,
                        const float* __restrict__ emb,
                        const float* __restrict__ Et,
                        const float* __restrict__ eNorm,
                        float* __restrict__ out,
                        float* __restrict__ lossAcc) {
    __shared__ float Xs[16][128];
    __shared__ float Es[16][128];
    __shared__ float redV[128][17];
    __shared__ int   redI[128][17];
    __shared__ int   idxs[128];
    __shared__ float wsum[4];

    const int t  = threadIdx.x;
    const int tx = t & 15;
    const int ty = t >> 4;
    const int n0  = blockIdx.x * 128;
    const int b   = n0 >> 10;        // /1024 (HW)
    const int hw0 = n0 & 1023;
    const float* latB = lat + b * (D_DIM * HW) + hw0;  // index: d*HW + r

    float best[8];
    int   bidx[8];
    #pragma unroll
    for (int i = 0; i < 8; ++i) { best[i] = 3.4e38f; bidx[i] = 0; }

    for (int kt = 0; kt < 8; ++kt) {
        const int k0 = kt * 128;
        float acc[8][8];
        #pragma unroll
        for (int i = 0; i < 8; ++i)
            #pragma unroll
            for (int j = 0; j < 8; ++j) acc[i][j] = 0.0f;

        for (int dt = 0; dt < 16; ++dt) {
            __syncthreads();  // protect LDS reads of previous d-slice
            {
                const int r   = t & 127;
                const int ddb = t >> 7;   // 0/1
                #pragma unroll
                for (int p = 0; p < 8; ++p) {
                    int dd = p * 2 + ddb;
                    int dg = dt * 16 + dd;
                    Xs[dd][r] = latB[dg * HW + r];
                    Es[dd][r] = Et[dg * K_CODES + k0 + r];
                }
            }
            __syncthreads();
            #pragma unroll
            for (int dd = 0; dd < 16; ++dd) {
                float4 xa = *reinterpret_cast<const float4*>(&Xs[dd][ty * 8]);
                float4 xb = *reinterpret_cast<const float4*>(&Xs[dd][ty * 8 + 4]);
                float xf[8] = {xa.x, xa.y, xa.z, xa.w, xb.x, xb.y, xb.z, xb.w};
                float ef[8];
                #pragma unroll
                for (int j = 0; j < 8; ++j) ef[j] = Es[dd][tx + j * 16];
                #pragma unroll
                for (int i = 0; i < 8; ++i)
                    #pragma unroll
                    for (int j = 0; j < 8; ++j)
                        acc[i][j] = fmaf(xf[i], ef[j], acc[i][j]);
            }
        }
        // score = ||e||^2 - 2 x.e  (||x||^2 is row-constant, irrelevant to argmin)
        #pragma unroll
        for (int j = 0; j < 8; ++j) {
            int k = k0 + tx + j * 16;
            float en = eNorm[k];
            #pragma unroll
            for (int i = 0; i < 8; ++i) {
                float s = en - 2.0f * acc[i][j];
                if (s < best[i] || (s == best[i] && k < bidx[i])) {
                    best[i] = s; bidx[i] = k;
                }
            }
        }
    }

    // cross-thread argmin reduce (16 tx per row)
    __syncthreads();
    #pragma unroll
    for (int i = 0; i < 8; ++i) {
        redV[ty * 8 + i][tx] = best[i];
        redI[ty * 8 + i][tx] = bidx[i];
    }
    __syncthreads();
    if (t < 128) {
        float bv = redV[t][0]; int bi = redI[t][0];
        #pragma unroll
        for (int j = 1; j < 16; ++j) {
            float v = redV[t][j]; int ii = redI[t][j];
            if (v < bv || (v == bv && ii < bi)) { bv = v; bi = ii; }
        }
        idxs[t] = bi;
    }
    __syncthreads();

    // gather + out write + loss accumulate
    float lsum = 0.0f;
    const int r     = t & 127;
    const int dbase = t >> 7;   // 0/1
    const float* erow = emb + idxs[r] * D_DIM;
    float* outB = out + b * (D_DIM * HW) + hw0;
    for (int p = 0; p < 128; ++p) {
        int d = p * 2 + dbase;
        float q = erow[d];
        float x = latB[d * HW + r];
        outB[d * HW + r] = q;
        float df = q - x;
        lsum = fmaf(df, df, lsum);
    }
    #pragma unroll
    for (int off = 32; off > 0; off >>= 1) lsum += __shfl_down(lsum, off, 64);
    int wid = t >> 6;
    if ((t & 63) == 0) wsum[wid] = lsum;
    __syncthreads();
    if (t == 0) atomicAdd(lossAcc, wsum[0] + wsum[1] + wsum[2] + wsum[3]);
}

// -------- finalize: write the two loss scalars --------
__global__ void finalize_kernel(const float* __restrict__ lossAcc,
                                float* __restrict__ out_tail) {
    float mse = *lossAcc * (1.0f / 16777216.0f);  // mean over N*D
    out_tail[0] = mse;          // embedding_loss
    out_tail[1] = 0.25f * mse;  // BETA * commitment_loss
}

extern "C" void kernel_launch(void* const* d_in, const int* in_sizes, int n_in,
                              void* d_out, int out_size, void* d_ws, size_t ws_size,
                              hipStream_t stream) {
    (void)in_sizes; (void)n_in; (void)out_size; (void)ws_size;
    const float* lat = (const float*)d_in[0];
    const float* emb = (const float*)d_in[1];
    float* out = (float*)d_out;

    float* Et      = (float*)d_ws;               // 256*1024 floats = 1 MB
    float* eNorm   = Et + D_DIM * K_CODES;       // 1024 floats
    float* lossAcc = eNorm + K_CODES;            // 1 float

    hipLaunchKernelGGL(enorm_kernel, dim3(K_CODES), dim3(64), 0, stream,
                       emb, eNorm, lossAcc);
    hipLaunchKernelGGL(transpose_kernel, dim3(16, 4), dim3(256), 0, stream,
                       emb, Et);
    hipLaunchKernelGGL(vq_main, dim3(512), dim3(256), 0, stream,
                       lat, emb, Et, eNorm, out, lossAcc);
    hipLaunchKernelGGL(finalize_kernel, dim3(1), dim3(1), 0, stream,
                       lossAcc, out + OUT_ELEMS);
}

// Round 2
// 236.476 us; speedup vs baseline: 2.5311x; 2.5311x over previous
//
#include <hip/hip_runtime.h>

typedef short bf16x8 __attribute__((ext_vector_type(8)));
typedef float f32x4 __attribute__((ext_vector_type(4)));

#define K_CODES 1024
#define D_DIM   256
#define HWSZ    1024
#define N_ROWS  65536
#define OUT_ELEMS 16777216

__device__ __forceinline__ unsigned short f2bf(float x) {
    unsigned int u = __float_as_uint(x);
    u += 0x7FFFu + ((u >> 16) & 1u);   // RNE
    return (unsigned short)(u >> 16);
}

// -------- prep: ||e_k||^2 per code + zero the loss accumulator --------
__global__ void enorm_kernel(const float* __restrict__ emb,
                             float* __restrict__ eNorm,
                             float* __restrict__ lossAcc) {
    int k = blockIdx.x;          // 1024 blocks
    int lane = threadIdx.x;      // 64 threads
    const float4* row = reinterpret_cast<const float4*>(emb + k * D_DIM);
    float4 v = row[lane];
    float s = v.x * v.x + v.y * v.y + v.z * v.z + v.w * v.w;
    #pragma unroll
    for (int off = 32; off > 0; off >>= 1) s += __shfl_down(s, off, 64);
    if (lane == 0) eNorm[k] = s;
    if (k == 0 && lane == 0) *lossAcc = 0.0f;
}

// -------- prep: pack E into B-fragment order --------
// frag fid = (ctile 0..63, dc 0..7); lane l elem e = E[ctile*16+(l&15)][dc*32+(l>>4)*8+e]
__global__ void pack_e(const float* __restrict__ emb, bf16x8* __restrict__ Ep) {
    int fid = blockIdx.x;        // 512
    int l = threadIdx.x;         // 64
    int ctile = fid >> 3, dc = fid & 7;
    const float* src = emb + (ctile * 16 + (l & 15)) * D_DIM + dc * 32 + ((l >> 4) << 3);
    float4 f0 = *reinterpret_cast<const float4*>(src);
    float4 f1 = *reinterpret_cast<const float4*>(src + 4);
    bf16x8 v;
    v[0] = (short)f2bf(f0.x); v[1] = (short)f2bf(f0.y);
    v[2] = (short)f2bf(f0.z); v[3] = (short)f2bf(f0.w);
    v[4] = (short)f2bf(f1.x); v[5] = (short)f2bf(f1.y);
    v[6] = (short)f2bf(f1.z); v[7] = (short)f2bf(f1.w);
    Ep[fid * 64 + l] = v;
}

// -------- prep: transpose+pack X into A-fragment order, accumulate sum(x^2) --------
// block: 128 rows x 256 d. LDS bf16 [128][256], quad(4-bf16)-granularity XOR swizzle.
__launch_bounds__(256, 2)
__global__ void pack_x(const float* __restrict__ lat, bf16x8* __restrict__ Xp,
                       float* __restrict__ lossAcc) {
    __shared__ unsigned int Xs[16384];   // 128 rows * 128 words = 64 KB
    __shared__ float ws4[4];
    const int t = threadIdx.x;
    const int R0 = blockIdx.x * 128;
    const float* latB = lat + (R0 >> 10) * (D_DIM * HWSZ) + (R0 & 1023);

    float xsq = 0.0f;
    #pragma unroll 4
    for (int it = 0; it < 64; ++it) {
        int flat = it * 256 + t;
        int r = flat & 127, dp = flat >> 7;       // d = 2*dp, 2*dp+1
        float v0 = latB[(2 * dp) * HWSZ + r];
        float v1 = latB[(2 * dp + 1) * HWSZ + r];
        xsq += v0 * v0 + v1 * v1;
        unsigned int u = (unsigned int)f2bf(v0) | ((unsigned int)f2bf(v1) << 16);
        // word index: r*128 + ((quad ^ (r&63))<<1) + (dp&1), quad = dp>>1
        Xs[r * 128 + (((dp >> 1) ^ (r & 63)) << 1) + (dp & 1)] = u;
    }
    #pragma unroll
    for (int off = 32; off > 0; off >>= 1) xsq += __shfl_down(xsq, off, 64);
    if ((t & 63) == 0) ws4[t >> 6] = xsq;
    __syncthreads();
    if (t == 0) atomicAdd(lossAcc, ws4[0] + ws4[1] + ws4[2] + ws4[3]);

    const unsigned long long* X64 = reinterpret_cast<const unsigned long long*>(Xs);
    const int RTb = blockIdx.x * 8;
    #pragma unroll 4
    for (int s = 0; s < 16; ++s) {
        int slot = s * 256 + t;
        int l = slot & 63, dc = (slot >> 6) & 7, rt = slot >> 9;
        int r = rt * 16 + (l & 15);
        int qa = dc * 8 + ((l >> 4) << 1);
        union { unsigned long long u[2]; bf16x8 v; } fr;
        fr.u[0] = X64[r * 64 + (qa ^ (r & 63))];
        fr.u[1] = X64[r * 64 + ((qa + 1) ^ (r & 63))];
        Xp[((RTb + rt) * 8 + dc) * 64 + l] = fr.v;
    }
}

// -------- main: MFMA distances + argmin + gather + out + loss --------
// 512 blocks x 256 thr (4 waves, 2x2). Block tile 128 rows x 128 cols, 8 col-iters.
__launch_bounds__(256, 2)
__global__ void vq_main(const bf16x8* __restrict__ Xp, const bf16x8* __restrict__ Ep,
                        const float* __restrict__ eNorm, const float* __restrict__ emb,
                        float* __restrict__ out, float* __restrict__ lossAcc) {
    __shared__ float eNormS[1024];
    __shared__ float redV[128][33];
    __shared__ int   redI[128][33];
    __shared__ int   idxs[128];
    __shared__ float Qs[32 * 257];
    __shared__ float wsum[2];

    const int t = threadIdx.x;
    const int lane = t & 63;
    const int wid = t >> 6;
    const int wr = wid >> 1, wc = wid & 1;
    const int l15 = lane & 15, lhi = lane >> 4;
    const int R0 = blockIdx.x * 128;
    const int RTb = blockIdx.x * 8 + wr * 4;

    #pragma unroll
    for (int p = 0; p < 4; ++p) eNormS[p * 256 + t] = eNorm[p * 256 + t];
    __syncthreads();

    float best[4][4];
    int   bidx[4][4];
    #pragma unroll
    for (int i = 0; i < 4; ++i)
        #pragma unroll
        for (int r = 0; r < 4; ++r) { best[i][r] = 3.4e38f; bidx[i][r] = 0; }

    for (int ct = 0; ct < 8; ++ct) {
        f32x4 acc[4][4];
        #pragma unroll
        for (int i = 0; i < 4; ++i)
            #pragma unroll
            for (int j = 0; j < 4; ++j) acc[i][j] = (f32x4){0.f, 0.f, 0.f, 0.f};

        #pragma unroll
        for (int dc = 0; dc < 8; ++dc) {
            bf16x8 a[4], b[4];
            #pragma unroll
            for (int i = 0; i < 4; ++i)
                a[i] = Xp[((RTb + i) * 8 + dc) * 64 + lane];
            #pragma unroll
            for (int j = 0; j < 4; ++j)
                b[j] = Ep[((ct * 8 + wc * 4 + j) * 8 + dc) * 64 + lane];
            #pragma unroll
            for (int i = 0; i < 4; ++i)
                #pragma unroll
                for (int j = 0; j < 4; ++j)
                    acc[i][j] = __builtin_amdgcn_mfma_f32_16x16x32_bf16(a[i], b[j], acc[i][j], 0, 0, 0);
        }
        #pragma unroll
        for (int j = 0; j < 4; ++j) {
            int k = ct * 128 + wc * 64 + j * 16 + l15;
            float en = eNormS[k];
            #pragma unroll
            for (int i = 0; i < 4; ++i)
                #pragma unroll
                for (int r = 0; r < 4; ++r) {
                    float s = en - 2.0f * acc[i][j][r];
                    if (s < best[i][r]) { best[i][r] = s; bidx[i][r] = k; }
                }
        }
    }

    // dump per-lane bests: row candidates live at (row, wc*16 + l15)
    const int cand = wc * 16 + l15;
    #pragma unroll
    for (int i = 0; i < 4; ++i)
        #pragma unroll
        for (int r = 0; r < 4; ++r) {
            int row = wr * 64 + i * 16 + lhi * 4 + r;
            redV[row][cand] = best[i][r];
            redI[row][cand] = bidx[i][r];
        }
    __syncthreads();

    float lsum = 0.0f;
    if (t < 128) {
        float bv = redV[t][0]; int bi = redI[t][0];
        #pragma unroll
        for (int c = 1; c < 32; ++c) {
            float v = redV[t][c]; int ii = redI[t][c];
            if (v < bv || (v == bv && ii < bi)) { bv = v; bi = ii; }
        }
        idxs[t] = bi;
        lsum = bv;   // = eNorm[bi] - 2*dot = per-row loss term (minus ||x||^2 part)
    }
    #pragma unroll
    for (int off = 32; off > 0; off >>= 1) lsum += __shfl_down(lsum, off, 64);
    if (t < 128 && (lane == 0)) wsum[wid] = lsum;
    __syncthreads();
    if (t == 0) atomicAdd(lossAcc, wsum[0] + wsum[1]);

    // epilogue: gather emb rows (coalesced) -> LDS transpose -> coalesced out writes
    float* outB = out + (R0 >> 10) * (D_DIM * HWSZ) + (R0 & 1023);
    for (int rc = 0; rc < 4; ++rc) {
        int r0 = rc * 32;
        #pragma unroll
        for (int p = 0; p < 8; ++p) {
            int slot = p * 256 + t;
            int rloc = slot >> 6, f4 = slot & 63;
            const float4 q = *reinterpret_cast<const float4*>(emb + idxs[r0 + rloc] * D_DIM + f4 * 4);
            float* dst = &Qs[rloc * 257 + f4 * 4];
            dst[0] = q.x; dst[1] = q.y; dst[2] = q.z; dst[3] = q.w;
        }
        __syncthreads();
        int rr = t & 31, dg = t >> 5;
        #pragma unroll
        for (int p = 0; p < 32; ++p) {
            int d = dg * 32 + p;
            outB[d * HWSZ + r0 + rr] = Qs[rr * 257 + d];
        }
        __syncthreads();
    }
}

// -------- finalize: write the two loss scalars --------
__global__ void finalize_kernel(const float* __restrict__ lossAcc,
                                float* __restrict__ out_tail) {
    float mse = *lossAcc * (1.0f / 16777216.0f);
    out_tail[0] = mse;          // embedding_loss
    out_tail[1] = 0.25f * mse;  // BETA * commitment_loss
}

extern "C" void kernel_launch(void* const* d_in, const int* in_sizes, int n_in,
                              void* d_out, int out_size, void* d_ws, size_t ws_size,
                              hipStream_t stream) {
    (void)in_sizes; (void)n_in; (void)out_size; (void)ws_size;
    const float* lat = (const float*)d_in[0];
    const float* emb = (const float*)d_in[1];
    float* out = (float*)d_out;

    char* ws = (char*)d_ws;
    bf16x8* Xp   = (bf16x8*)ws;                                  // 32 MB
    bf16x8* Ep   = (bf16x8*)(ws + (32u << 20));                  // 512 KB
    float* eNorm = (float*)(ws + (32u << 20) + (512u << 10));    // 4 KB
    float* lossAcc = eNorm + K_CODES;                            // 4 B

    hipLaunchKernelGGL(enorm_kernel, dim3(K_CODES), dim3(64), 0, stream,
                       emb, eNorm, lossAcc);
    hipLaunchKernelGGL(pack_e, dim3(512), dim3(64), 0, stream, emb, Ep);
    hipLaunchKernelGGL(pack_x, dim3(512), dim3(256), 0, stream, lat, Xp, lossAcc);
    hipLaunchKernelGGL(vq_main, dim3(512), dim3(256), 0, stream,
                       Xp, Ep, eNorm, emb, out, lossAcc);
    hipLaunchKernelGGL(finalize_kernel, dim3(1), dim3(1), 0, stream,
                       lossAcc, out + OUT_ELEMS);
}